// Round 3
// baseline (438.998 us; speedup 1.0000x reference)
//
#include <hip/hip_runtime.h>
#include <hip/hip_bf16.h>
#include <stdint.h>

// Problem constants (fixed by reference setup_inputs)
#define NX 16384   // rows of x
#define NC 4096    // rows of prototype (= output cols)
#define DIM 1024   // feature dim (K)

typedef __attribute__((ext_vector_type(8))) short bf16x8;   // 8 bf16 = 4 VGPRs
typedef __attribute__((ext_vector_type(4))) float f32x4;

// ---------- helpers ----------

__device__ inline unsigned short f2bf_rn(float f) {
  union { float f; unsigned u; } v; v.f = f;
  unsigned u = v.u;
  unsigned r = (u + 0x7FFFu + ((u >> 16) & 1u)) >> 16;  // round-nearest-even
  return (unsigned short)r;
}

__device__ inline void gload_lds16(const void* g, void* l) {
  // width-16 direct global->LDS. LDS dest = wave-uniform base + lane*16 (linear).
  __builtin_amdgcn_global_load_lds(
      (const __attribute__((address_space(1))) void*)g,
      (__attribute__((address_space(3))) void*)l,
      16, 0, 0);
}

__device__ inline f32x4 mfma_bf16_16x16x32(bf16x8 a, bf16x8 b, f32x4 c) {
  asm("v_mfma_f32_16x16x32_bf16 %0, %1, %2, %0" : "+v"(c) : "v"(a), "v"(b));
  return c;
}

// ---------- kernel 1: fused fp32 -> bf16 + fp32 row sum-of-squares ----------
// one wave per row; 4 waves/block; rows = NX (x) then NC (prototype).

__global__ __launch_bounds__(256) void convert_all(
    const float* __restrict__ x, const float* __restrict__ p,
    unsigned short* __restrict__ xb, unsigned short* __restrict__ pb,
    float* __restrict__ xsq, float* __restrict__ psq) {
  const int gw = blockIdx.x * 4 + (threadIdx.x >> 6);
  const int lane = threadIdx.x & 63;
  const float* src; unsigned short* dst; float* sq; int row;
  if (gw < NX) { src = x; dst = xb; sq = xsq; row = gw; }
  else         { src = p; dst = pb; sq = psq; row = gw - NX; }
  const size_t base = (size_t)row * DIM;

  float s = 0.f;
  #pragma unroll
  for (int j = 0; j < 4; ++j) {
    const float4 v = *(const float4*)(src + base + j * 256 + lane * 4);
    s += v.x * v.x + v.y * v.y + v.z * v.z + v.w * v.w;
    ushort4 o;
    o.x = f2bf_rn(v.x); o.y = f2bf_rn(v.y);
    o.z = f2bf_rn(v.z); o.w = f2bf_rn(v.w);
    *(ushort4*)(dst + base + j * 256 + lane * 4) = o;
  }
  #pragma unroll
  for (int off = 32; off; off >>= 1) s += __shfl_xor(s, off, 64);
  if (lane == 0) sq[row] = s;
}

// ---------- kernel 2: 256x256 bf16 MFMA GEMM + distance epilogue ----------
// BM=BN=256, BK=64, 512 thr = 8 waves (2M x 4N). Per wave: 128x64 output =
// acc[8][4] of 16x16 frags. Double-buffered 128KB LDS, counted vmcnt(8)
// pipeline (prefetch distance 2 K-tiles), T2 swizzle byte^=((row&7)<<4)
// via pre-swizzled global source (linear gload_lds dest) + swizzled ds_read.

#define BM 256
#define BN 256
#define BK 64
#define NT (DIM / BK)   // 16

__global__ __launch_bounds__(512, 2) void dist_gemm(
    const unsigned short* __restrict__ xb,   // [NX][DIM] bf16
    const unsigned short* __restrict__ pb,   // [NC][DIM] bf16
    const float* __restrict__ xsq,           // [NX]
    const float* __restrict__ psq,           // [NC]
    float* __restrict__ out) {               // [NX][NC]
  extern __shared__ char lds[];   // 131072 B: [buf0: A 32K | B 32K][buf1: A | B]

  const int tid  = threadIdx.x;
  const int wid  = tid >> 6;      // 0..7
  const int lane = tid & 63;
  const int wm = wid >> 2;        // 0..1
  const int wn = wid & 3;         // 0..3

  // XCD-bijective supertile mapping: 1024 wgs, 8 XCDs, 4x4 supertiles.
  // XCD x covers tm in [x*8, x*8+8), all tn; within chunk, 4x4 groups.
  const int bid = blockIdx.x;
  const int xcd = bid & 7;
  const int idx = bid >> 3;               // 0..127
  const int g   = idx >> 4;               // 0..7 -> (gm = g&1, gn = g>>1)
  const int l4  = idx & 15;
  const int tm  = xcd * 8 + (g & 1) * 4 + (l4 >> 2);   // 0..63
  const int tn  = (g >> 1) * 4 + (l4 & 3);             // 0..15
  const int row0 = tm * BM, col0 = tn * BN;

  // --- staging constants ---
  // chunk c = it*512 + wid*64 + lane covers LDS bytes [c*16, c*16+16) linearly
  // within a 32KB [256][64]bf16 tile (row = c>>3, colbyte = (c&7)*16).
  // Pre-swizzle the SOURCE: colbyte' = colbyte ^ ((row&7)<<4).
  const int srow = wid * 8 + (lane >> 3);                 // + it*64 per iter
  const int scb  = ((lane & 7) ^ (lane >> 3)) << 4;       // pre-swizzled colbyte
  const char* gA = (const char*)xb + (size_t)(row0 + srow) * (DIM * 2) + scb;
  const char* gB = (const char*)pb + (size_t)(col0 + srow) * (DIM * 2) + scb;

  // --- read-side offsets (swizzled) ---
  // frag(m|n, ks): row = base + m*16 + (lane&15); colbyte = ks*64 + (lane>>4)*16
  // lds byte = row*128 + (colbyte ^ ((lane&7)<<4))   [row&7 == lane&7]
  const int sx   = (lane & 7) << 4;
  const int hi16 = (lane >> 4) << 4;
  const int arow = (wm * 128 + (lane & 15)) * 128;   // + m*2048
  const int brow = (wn * 64  + (lane & 15)) * 128;   // + n*2048
  const int csw0 = (hi16 + 0)  ^ sx;
  const int csw1 = (hi16 + 64) ^ sx;

  f32x4 acc[8][4] = {};

#define STAGE(kt, bufsel) do {                                               \
    char* lA_ = lds + (bufsel) * 65536;                                      \
    char* lB_ = lA_ + 32768;                                                 \
    _Pragma("unroll")                                                        \
    for (int it = 0; it < 4; ++it) {                                         \
      gload_lds16(gA + (size_t)(kt) * 128 + (size_t)it * 64 * (DIM * 2),     \
                  lA_ + it * 8192 + wid * 1024);                             \
      gload_lds16(gB + (size_t)(kt) * 128 + (size_t)it * 64 * (DIM * 2),     \
                  lB_ + it * 8192 + wid * 1024);                             \
    }                                                                        \
  } while (0)

#define COMPUTE(bufsel) do {                                                 \
    const char* lA_ = lds + (bufsel) * 65536;                                \
    const char* lB_ = lA_ + 32768;                                           \
    bf16x8 a[8], b[4];                                                       \
    _Pragma("unroll")                                                        \
    for (int m = 0; m < 8; ++m)                                              \
      a[m] = *(const bf16x8*)(lA_ + arow + m * 2048 + csw0);                 \
    _Pragma("unroll")                                                        \
    for (int n = 0; n < 4; ++n)                                              \
      b[n] = *(const bf16x8*)(lB_ + brow + n * 2048 + csw0);                 \
    __builtin_amdgcn_s_setprio(1);                                           \
    _Pragma("unroll")                                                        \
    for (int m = 0; m < 8; ++m)                                              \
      _Pragma("unroll")                                                      \
      for (int n = 0; n < 4; ++n)                                            \
        acc[m][n] = mfma_bf16_16x16x32(a[m], b[n], acc[m][n]);               \
    __builtin_amdgcn_s_setprio(0);                                           \
    _Pragma("unroll")                                                        \
    for (int m = 0; m < 8; ++m)                                              \
      a[m] = *(const bf16x8*)(lA_ + arow + m * 2048 + csw1);                 \
    _Pragma("unroll")                                                        \
    for (int n = 0; n < 4; ++n)                                              \
      b[n] = *(const bf16x8*)(lB_ + brow + n * 2048 + csw1);                 \
    __builtin_amdgcn_s_setprio(1);                                           \
    _Pragma("unroll")                                                        \
    for (int m = 0; m < 8; ++m)                                              \
      _Pragma("unroll")                                                      \
      for (int n = 0; n < 4; ++n)                                            \
        acc[m][n] = mfma_bf16_16x16x32(a[m], b[n], acc[m][n]);               \
    __builtin_amdgcn_s_setprio(0);                                           \
  } while (0)

  // prologue: tile 0 -> buf0
  STAGE(0, 0);

  // main loop: stage t+1 into the buffer whose readers drained at iter t-1;
  // vmcnt(8) = counted wait (tile t landed; tile t+1's 8 loads stay in flight).
  #pragma unroll 2
  for (int t = 0; t < NT - 1; ++t) {
    STAGE(t + 1, (t + 1) & 1);
    asm volatile("s_waitcnt vmcnt(8)" ::: "memory");
    __builtin_amdgcn_s_barrier();
    asm volatile("" ::: "memory");
    COMPUTE(t & 1);
    asm volatile("" ::: "memory");
    __builtin_amdgcn_s_barrier();
  }
  // peeled last iteration: nothing left to stage -> full drain
  asm volatile("s_waitcnt vmcnt(0)" ::: "memory");
  __builtin_amdgcn_s_barrier();
  asm volatile("" ::: "memory");
  COMPUTE((NT - 1) & 1);

#undef STAGE
#undef COMPUTE

  // epilogue: d = xsq[r] + psq[c] - 2*cross
  // C/D layout (m89): col = lane&15, row = (lane>>4)*4 + reg.
  const int orow = row0 + wm * 128 + ((lane >> 4) << 2);
  const int ocol = col0 + wn * 64 + (lane & 15);
  float pv[4];
  #pragma unroll
  for (int n = 0; n < 4; ++n) pv[n] = psq[ocol + n * 16];

  #pragma unroll
  for (int m = 0; m < 8; ++m) {
    #pragma unroll
    for (int ri = 0; ri < 4; ++ri) {
      const int r = orow + m * 16 + ri;
      const float xv = xsq[r];
      #pragma unroll
      for (int n = 0; n < 4; ++n)
        out[(size_t)r * NC + ocol + n * 16] = xv + pv[n] - 2.0f * acc[m][n][ri];
    }
  }
}

// ---------- launch ----------

extern "C" void kernel_launch(void* const* d_in, const int* in_sizes, int n_in,
                              void* d_out, int out_size, void* d_ws, size_t ws_size,
                              hipStream_t stream) {
  const float* x = (const float*)d_in[0];   // [16384][1024] fp32
  const float* p = (const float*)d_in[1];   // [4096][1024] fp32
  float* out = (float*)d_out;               // [16384][4096] fp32

  // workspace layout (40.1 MB total)
  char* ws = (char*)d_ws;
  unsigned short* xb  = (unsigned short*)ws;                          // 32 MB
  unsigned short* pbb = (unsigned short*)(ws + (size_t)NX * DIM * 2); // 8 MB
  float* xsq = (float*)(ws + (size_t)NX * DIM * 2 + (size_t)NC * DIM * 2);
  float* psq = xsq + NX;

  convert_all<<<(NX + NC) / 4, 256, 0, stream>>>(x, p, xb, pbb, xsq, psq);

  // 128 KB dynamic LDS needs explicit opt-in (static __shared__ caps at 64 KB)
  static int attr_done = 0;
  (void)hipFuncSetAttribute((const void*)dist_gemm,
                            hipFuncAttributeMaxDynamicSharedMemorySize, 131072);
  (void)attr_done;

  dist_gemm<<<dim3((NX / BM) * (NC / BN)), dim3(512), 131072, stream>>>(
      xb, pbb, xsq, psq, out);
}